// Round 12
// baseline (319.297 us; speedup 1.0000x reference)
//
#include <hip/hip_runtime.h>
#include <stdint.h>

#define BATCH 4
#define SEQ   2048
#define NHEAD 16
#define DHEAD 64
#define HID   1024

typedef __bf16 bf16x8 __attribute__((ext_vector_type(8)));
typedef __bf16 bf16x4 __attribute__((ext_vector_type(4)));
typedef float  f32x4  __attribute__((ext_vector_type(4)));
typedef short  s16x4  __attribute__((ext_vector_type(4)));

// load 8 contiguous f32, round to bf16x8
__device__ __forceinline__ bf16x8 load8f(const float* p) {
  const f32x4 a = ((const f32x4*)p)[0];
  const f32x4 b = ((const f32x4*)p)[1];
  bf16x8 r;
#pragma unroll
  for (int i = 0; i < 4; ++i) r[i] = (__bf16)a[i];
#pragma unroll
  for (int i = 0; i < 4; ++i) r[4 + i] = (__bf16)b[i];
  return r;
}

__device__ __forceinline__ s16x4 as_s16x4(bf16x4 v) {
  s16x4 r; __builtin_memcpy(&r, &v, 8); return r;
}

// async global->LDS, 16B per lane. LDS dest = wave-uniform base + lane*16.
__device__ __forceinline__ void gload_lds16(const __bf16* g, __bf16* l) {
  __builtin_amdgcn_global_load_lds(
      (const __attribute__((address_space(1))) uint32_t*)g,
      (__attribute__((address_space(3))) uint32_t*)l,
      16, 0, 0);
}

// ---------------------------------------------------------------------------
// fused f32 -> bf16 conversion: x (1048576 units) + Wq/Wk/Wv (131072 each)
// in ONE launch. 8 elements/thread.
// ---------------------------------------------------------------------------
#define XUNITS 1048576
#define WUNITS 131072

__global__ __launch_bounds__(256) void cvt_fused_kernel(
    const float* __restrict__ x,
    const float* __restrict__ Wq, const float* __restrict__ Wk,
    const float* __restrict__ Wv,
    __bf16* __restrict__ xb, __bf16* __restrict__ Wb) {
  const int i = blockIdx.x * 256 + threadIdx.x;
  const float* s;
  __bf16* d;
  if (i < XUNITS) {
    s = x + (size_t)i * 8;
    d = xb + (size_t)i * 8;
  } else {
    const int j = i - XUNITS;
    const int w = j >> 17;          // /131072
    const int o = j & (WUNITS - 1);
    s = (w == 0 ? Wq : w == 1 ? Wk : Wv) + (size_t)o * 8;
    d = Wb + ((size_t)w << 20) + (size_t)o * 8;
  }
  *(bf16x8*)d = load8f(s);
}

#define ASTRIDE 40
#define BK 32

// ---------------------------------------------------------------------------
// qkv FUSED (r9 verbatim -- best measured ~131 us): one block does Q,K,V for
// its 128x128 tile; A staged once/window + 3 B-tiles -> 24 MFMA per barrier
// window. 2-phase dbuf, gload_lds w16, T1 XCD swizzle.
// ---------------------------------------------------------------------------
__global__ __launch_bounds__(512) void qkv_fused_kernel(
    const __bf16* __restrict__ xb, const __bf16* __restrict__ Wb,
    const float* __restrict__ bq, const float* __restrict__ bk,
    const float* __restrict__ bv, const float* __restrict__ sp,
    float* __restrict__ qout, __bf16* __restrict__ Kws, __bf16* __restrict__ Vws)
{
  const int d    = blockIdx.x + (blockIdx.y << 3);
  const int t    = (d & 7) * 64 + (d >> 3);
  const int n0   = (t & 7) * 128;
  const int m0   = (t >> 3) * 128;

  const int tid  = threadIdx.x;
  const int lane = tid & 63;
  const int quad = lane >> 4;
  const int l16  = lane & 15;
  const int wave = tid >> 6;          // 0..7
  const int wr   = wave >> 1, wc = wave & 1;

  __shared__ __align__(16) __bf16 As[2][128 * BK];      // 16 KB
  __shared__ __align__(16) __bf16 Bs[3][2][128 * BK];   // 48 KB

  const int srow = wave * 16 + (lane >> 2);
  const int scol = (lane & 3) * 8;
  const __bf16* aglb  = xb + (size_t)(m0 + srow) * HID + scol;
  const __bf16* bglb0 = Wb + (size_t)(n0 + srow) * HID + scol;            // Wq
  const __bf16* bglb1 = bglb0 + (size_t)HID * HID;                        // Wk
  const __bf16* bglb2 = bglb0 + (size_t)2 * HID * HID;                    // Wv
  const int woff = wave * 512;        // wave-uniform LDS offset (elements)

  f32x4 aQ[2][4], aK[2][4], aV[2][4];
  const f32x4 z = {0.f, 0.f, 0.f, 0.f};
#pragma unroll
  for (int i = 0; i < 2; ++i)
#pragma unroll
    for (int j = 0; j < 4; ++j) { aQ[i][j] = z; aK[i][j] = z; aV[i][j] = z; }

  // prologue: stage tile 0 into buffer 0, drain
  gload_lds16(aglb,  &As[0][woff]);
  gload_lds16(bglb0, &Bs[0][0][woff]);
  gload_lds16(bglb1, &Bs[1][0][woff]);
  gload_lds16(bglb2, &Bs[2][0][woff]);
  __syncthreads();

#pragma unroll 1
  for (int k0 = 0; k0 < HID; k0 += 2 * BK) {
    // ---- half A: compute buf0, prefetch k0+BK -> buf1 ----
    {
      gload_lds16(aglb  + (k0 + BK), &As[1][woff]);
      gload_lds16(bglb0 + (k0 + BK), &Bs[0][1][woff]);
      gload_lds16(bglb1 + (k0 + BK), &Bs[1][1][woff]);
      gload_lds16(bglb2 + (k0 + BK), &Bs[2][1][woff]);

      bf16x8 af[2];
#pragma unroll
      for (int mt = 0; mt < 2; ++mt)
        af[mt] = *(const bf16x8*)(&As[0][(wr * 32 + mt * 16 + l16) * BK + quad * 8]);
      {
        bf16x8 bfr[4];
#pragma unroll
        for (int nt = 0; nt < 4; ++nt)
          bfr[nt] = *(const bf16x8*)(&Bs[0][0][(wc * 64 + nt * 16 + l16) * BK + quad * 8]);
#pragma unroll
        for (int mt = 0; mt < 2; ++mt)
#pragma unroll
          for (int nt = 0; nt < 4; ++nt)
            aQ[mt][nt] = __builtin_amdgcn_mfma_f32_16x16x32_bf16(af[mt], bfr[nt], aQ[mt][nt], 0, 0, 0);
      }
      {
        bf16x8 bfr[4];
#pragma unroll
        for (int nt = 0; nt < 4; ++nt)
          bfr[nt] = *(const bf16x8*)(&Bs[1][0][(wc * 64 + nt * 16 + l16) * BK + quad * 8]);
#pragma unroll
        for (int mt = 0; mt < 2; ++mt)
#pragma unroll
          for (int nt = 0; nt < 4; ++nt)
            aK[mt][nt] = __builtin_amdgcn_mfma_f32_16x16x32_bf16(af[mt], bfr[nt], aK[mt][nt], 0, 0, 0);
      }
      {
        bf16x8 bfr[4];
#pragma unroll
        for (int nt = 0; nt < 4; ++nt)
          bfr[nt] = *(const bf16x8*)(&Bs[2][0][(wc * 64 + nt * 16 + l16) * BK + quad * 8]);
        // swapped operands -> V^T output
#pragma unroll
        for (int mt = 0; mt < 2; ++mt)
#pragma unroll
          for (int nt = 0; nt < 4; ++nt)
            aV[mt][nt] = __builtin_amdgcn_mfma_f32_16x16x32_bf16(bfr[nt], af[mt], aV[mt][nt], 0, 0, 0);
      }
      __syncthreads();
    }
    // ---- half B: compute buf1, prefetch k0+2*BK -> buf0 ----
    {
      if (k0 + 2 * BK < HID) {
        gload_lds16(aglb  + (k0 + 2 * BK), &As[0][woff]);
        gload_lds16(bglb0 + (k0 + 2 * BK), &Bs[0][0][woff]);
        gload_lds16(bglb1 + (k0 + 2 * BK), &Bs[1][0][woff]);
        gload_lds16(bglb2 + (k0 + 2 * BK), &Bs[2][0][woff]);
      }

      bf16x8 af[2];
#pragma unroll
      for (int mt = 0; mt < 2; ++mt)
        af[mt] = *(const bf16x8*)(&As[1][(wr * 32 + mt * 16 + l16) * BK + quad * 8]);
      {
        bf16x8 bfr[4];
#pragma unroll
        for (int nt = 0; nt < 4; ++nt)
          bfr[nt] = *(const bf16x8*)(&Bs[0][1][(wc * 64 + nt * 16 + l16) * BK + quad * 8]);
#pragma unroll
        for (int mt = 0; mt < 2; ++mt)
#pragma unroll
          for (int nt = 0; nt < 4; ++nt)
            aQ[mt][nt] = __builtin_amdgcn_mfma_f32_16x16x32_bf16(af[mt], bfr[nt], aQ[mt][nt], 0, 0, 0);
      }
      {
        bf16x8 bfr[4];
#pragma unroll
        for (int nt = 0; nt < 4; ++nt)
          bfr[nt] = *(const bf16x8*)(&Bs[1][1][(wc * 64 + nt * 16 + l16) * BK + quad * 8]);
#pragma unroll
        for (int mt = 0; mt < 2; ++mt)
#pragma unroll
          for (int nt = 0; nt < 4; ++nt)
            aK[mt][nt] = __builtin_amdgcn_mfma_f32_16x16x32_bf16(af[mt], bfr[nt], aK[mt][nt], 0, 0, 0);
      }
      {
        bf16x8 bfr[4];
#pragma unroll
        for (int nt = 0; nt < 4; ++nt)
          bfr[nt] = *(const bf16x8*)(&Bs[2][1][(wc * 64 + nt * 16 + l16) * BK + quad * 8]);
#pragma unroll
        for (int mt = 0; mt < 2; ++mt)
#pragma unroll
          for (int nt = 0; nt < 4; ++nt)
            aV[mt][nt] = __builtin_amdgcn_mfma_f32_16x16x32_bf16(bfr[nt], af[mt], aV[mt][nt], 0, 0, 0);
      }
      __syncthreads();
    }
  }

  // ---- epilogue Q: RoPE + f32 store ----
#pragma unroll
  for (int mt = 0; mt < 2; ++mt) {
#pragma unroll
    for (int nt = 0; nt < 4; ++nt) {
      const int n = n0 + wc * 64 + nt * 16 + l16;
      const int h = n >> 6, dd = n & 63;
      const float bval = bq[n];
#pragma unroll
      for (int v = 0; v < 4; ++v) {
        const int m = m0 + wr * 32 + mt * 16 + quad * 4 + v;
        const int b = m >> 11, s = m & (SEQ - 1);
        float val = aQ[mt][nt][v] + bval;
        float p  = __shfl_xor(val, 1);
        float sn = sp[s * 64 + (dd >> 1)];
        float cs = sp[s * 64 + 32 + (dd >> 1)];
        val = val * cs + ((dd & 1) ? p : -p) * sn;
        qout[((size_t)b * SEQ + s) * HID + n] = val;
      }
    }
  }
  // ---- epilogue K: RoPE + bf16 store to Kws[B,H,S,DH] ----
#pragma unroll
  for (int mt = 0; mt < 2; ++mt) {
#pragma unroll
    for (int nt = 0; nt < 4; ++nt) {
      const int n = n0 + wc * 64 + nt * 16 + l16;
      const int h = n >> 6, dd = n & 63;
      const float bval = bk[n];
#pragma unroll
      for (int v = 0; v < 4; ++v) {
        const int m = m0 + wr * 32 + mt * 16 + quad * 4 + v;
        const int b = m >> 11, s = m & (SEQ - 1);
        float val = aK[mt][nt][v] + bval;
        float p  = __shfl_xor(val, 1);
        float sn = sp[s * 64 + (dd >> 1)];
        float cs = sp[s * 64 + 32 + (dd >> 1)];
        val = val * cs + ((dd & 1) ? p : -p) * sn;
        Kws[(((size_t)b * NHEAD + h) * SEQ + s) * DHEAD + dd] = (__bf16)val;
      }
    }
  }
  // ---- epilogue V: V^T bf16 store to Vws[B,H,DH,S] (swapped layout) ----
#pragma unroll
  for (int mt = 0; mt < 2; ++mt) {
#pragma unroll
    for (int nt = 0; nt < 4; ++nt) {
      const int m = m0 + wr * 32 + mt * 16 + l16;   // X-row from l16 (swapped)
      const int b = m >> 11, s = m & (SEQ - 1);
#pragma unroll
      for (int v = 0; v < 4; ++v) {
        const int n = n0 + wc * 64 + nt * 16 + quad * 4 + v;
        const int h = n >> 6, dd = n & 63;
        float val = aV[mt][nt][v] + bv[n];
        Vws[(((size_t)b * NHEAD + h) * DHEAD + dd) * SEQ + s] = (__bf16)val;
      }
    }
  }
}

// ---------------------------------------------------------------------------
// qkv fallback (ws too small): f32 inputs, 512-thread version. (unchanged)
// ---------------------------------------------------------------------------
__global__ __launch_bounds__(512) void qkv_f32_kernel(
    const float* __restrict__ x,
    const float* __restrict__ Wq, const float* __restrict__ bq,
    const float* __restrict__ Wk, const float* __restrict__ bk,
    const float* __restrict__ Wv, const float* __restrict__ bv,
    const float* __restrict__ sp,
    float* __restrict__ qout, __bf16* __restrict__ Kws, __bf16* __restrict__ Vws)
{
  const int widx = blockIdx.z;
  const float* __restrict__ W    = (widx == 0) ? Wq : (widx == 1) ? Wk : Wv;
  const float* __restrict__ bias = (widx == 0) ? bq : (widx == 1) ? bk : bv;

  const int m0   = blockIdx.y * 128;
  const int n0   = blockIdx.x * 128;
  const int tid  = threadIdx.x;
  const int lane = tid & 63;
  const int quad = lane >> 4;
  const int l16  = lane & 15;
  const int wave = tid >> 6;
  const int wr   = wave >> 1, wc = wave & 1;

  __shared__ __align__(16) __bf16 As[128 * ASTRIDE];
  __shared__ __align__(16) __bf16 Bs[128 * ASTRIDE];

  const int srow = tid >> 2;
  const int scb  = tid & 3;

  f32x4 acc[2][4];
  const f32x4 z = {0.f, 0.f, 0.f, 0.f};
#pragma unroll
  for (int i = 0; i < 2; ++i)
#pragma unroll
    for (int j = 0; j < 4; ++j) acc[i][j] = z;

  bf16x8 areg = load8f(x + (size_t)(m0 + srow) * HID + scb * 8);
  bf16x8 breg = load8f(W + (size_t)(n0 + srow) * HID + scb * 8);

  for (int k0 = 0; k0 < HID; k0 += 32) {
    __syncthreads();
    *(bf16x8*)(As + srow * ASTRIDE + scb * 8) = areg;
    *(bf16x8*)(Bs + srow * ASTRIDE + scb * 8) = breg;
    __syncthreads();

    if (k0 + 32 < HID) {
      areg = load8f(x + (size_t)(m0 + srow) * HID + (k0 + 32) + scb * 8);
      breg = load8f(W + (size_t)(n0 + srow) * HID + (k0 + 32) + scb * 8);
    }

    bf16x8 af[2], bfr[4];
#pragma unroll
    for (int mt = 0; mt < 2; ++mt)
      af[mt] = *(const bf16x8*)(As + (wr * 32 + mt * 16 + l16) * ASTRIDE + quad * 8);
#pragma unroll
    for (int nt = 0; nt < 4; ++nt)
      bfr[nt] = *(const bf16x8*)(Bs + (wc * 64 + nt * 16 + l16) * ASTRIDE + quad * 8);

    if (widx < 2) {
#pragma unroll
      for (int mt = 0; mt < 2; ++mt)
#pragma unroll
        for (int nt = 0; nt < 4; ++nt)
          acc[mt][nt] = __builtin_amdgcn_mfma_f32_16x16x32_bf16(af[mt], bfr[nt], acc[mt][nt], 0, 0, 0);
    } else {
#pragma unroll
      for (int mt = 0; mt < 2; ++mt)
#pragma unroll
        for (int nt = 0; nt < 4; ++nt)
          acc[mt][nt] = __builtin_amdgcn_mfma_f32_16x16x32_bf16(bfr[nt], af[mt], acc[mt][nt], 0, 0, 0);
    }
  }

  if (widx < 2) {
#pragma unroll
    for (int mt = 0; mt < 2; ++mt) {
#pragma unroll
      for (int nt = 0; nt < 4; ++nt) {
        const int n = n0 + wc * 64 + nt * 16 + l16;
        const int h = n >> 6, dd = n & 63;
        const float bval = bias[n];
#pragma unroll
        for (int v = 0; v < 4; ++v) {
          const int m = m0 + wr * 32 + mt * 16 + quad * 4 + v;
          const int b = m >> 11, s = m & (SEQ - 1);
          float val = acc[mt][nt][v] + bval;
          float p  = __shfl_xor(val, 1);
          float sn = sp[s * 64 + (dd >> 1)];
          float cs = sp[s * 64 + 32 + (dd >> 1)];
          val = val * cs + ((dd & 1) ? p : -p) * sn;
          if (widx == 0) {
            qout[((size_t)b * SEQ + s) * HID + n] = val;
          } else {
            Kws[(((size_t)b * NHEAD + h) * SEQ + s) * DHEAD + dd] = (__bf16)val;
          }
        }
      }
    }
  } else {
#pragma unroll
    for (int mt = 0; mt < 2; ++mt) {
#pragma unroll
      for (int nt = 0; nt < 4; ++nt) {
        const int m = m0 + wr * 32 + mt * 16 + l16;
        const int b = m >> 11, s = m & (SEQ - 1);
#pragma unroll
        for (int v = 0; v < 4; ++v) {
          const int n = n0 + wc * 64 + nt * 16 + quad * 4 + v;
          const int h = n >> 6, dd = n & 63;
          float val = acc[mt][nt][v] + bias[n];
          Vws[(((size_t)b * NHEAD + h) * DHEAD + dd) * SEQ + s] = (__bf16)val;
        }
      }
    }
  }
}

// ---------------------------------------------------------------------------
// attn: mq=2 q-row amortization + PS-free register-P PV (both pieces
// individually verified; r4's mq failure was occupancy -- 8 waves/CU from
// 55KB LDS -- fixed here by PS-free 18.4KB LDS + 512 threads).
// 512 thr / 8 waves; wave owns q-rows [wave*32, +32) as TWO 16-row frags;
// q-tile 256, grid 512 blocks (2/CU, 16 waves/CU). Per wave-tile: 26 DS
// instrs serve 2x q-rows -> per-CU DS demand ~halved vs r7 (the 73%-
// saturated pipe). S^T: kf[nt] read once, feeds both mq MFMAs. PV: K=16
// MFMA, P direct from registers (r11-verified layout match).
// ---------------------------------------------------------------------------
#define KT 64
#define QSTR 72
#define LOG2E 1.44269504088896340736f
#define PSHIFT 12.0f

__global__ __launch_bounds__(512) void attn_kernel(
    float* __restrict__ qo,
    const __bf16* __restrict__ Kws, const __bf16* __restrict__ Vws,
    const float* __restrict__ mask)
{
  // XCD swizzle over 512 blocks: d = x + 8y; t = (d&7)*64 + d>>3;
  // XCD j owns t in [64j,64j+64) -> bh in [8j,8j+8) (4MB K/V, L2-fit).
  const int dsw  = blockIdx.x + (blockIdx.y << 3);
  const int tsw  = (dsw & 7) * 64 + (dsw >> 3);
  const int bh   = tsw >> 3;
  const int q0   = (tsw & 7) * 256;

  const int b    = bh >> 4, h = bh & 15;
  const int tid  = threadIdx.x;
  const int lane = tid & 63;
  const int wave = tid >> 6;          // 0..7
  const int quad = lane >> 4;
  const int l16  = lane & 15;

  __shared__ __align__(16) __bf16 Ks[64 * QSTR];    // [t][k]
  __shared__ __align__(16) __bf16 Vts[64 * QSTR];   // [d][t]

  const __bf16* kbase = Kws + (size_t)bh * SEQ * DHEAD;
  const __bf16* vbase = Vws + (size_t)bh * DHEAD * SEQ;

  // ---- Q fragments (B-operand): q-row = wave*32 + mq*16 + l16 ----
  bf16x8 qf[2][2];
#pragma unroll
  for (int mq = 0; mq < 2; ++mq)
#pragma unroll
    for (int ks = 0; ks < 2; ++ks)
      qf[mq][ks] = load8f(qo + ((size_t)b * SEQ + q0 + wave * 32 + mq * 16 + l16) * HID
                             + h * DHEAD + ks * 32 + quad * 8);

  f32x4 o_acc[2][4];   // [mq][dblk], C-layout: d=quad*4+v, q=l16
  const f32x4 z = {0.f, 0.f, 0.f, 0.f};
#pragma unroll
  for (int mq = 0; mq < 2; ++mq)
#pragma unroll
    for (int i = 0; i < 4; ++i) o_acc[mq][i] = z;
  float l_part[2] = {0.f, 0.f};

  const int qrow = tid >> 3;          // 0..63
  const int qcb  = tid & 7;           // col block 0..7

  bf16x8 kreg = *(const bf16x8*)(kbase + (size_t)qrow * DHEAD + qcb * 8);
  bf16x8 vreg = *(const bf16x8*)(vbase + (size_t)qrow * SEQ + qcb * 8);

  const float SC2 = 0.125f * LOG2E;

  for (int t0 = 0; t0 < SEQ; t0 += KT) {
    *(bf16x8*)(Ks  + qrow * QSTR + qcb * 8) = kreg;
    *(bf16x8*)(Vts + qrow * QSTR + qcb * 8) = vreg;
    __syncthreads();

    if (t0 + KT < SEQ) {
      kreg = *(const bf16x8*)(kbase + (size_t)(t0 + KT + qrow) * DHEAD + qcb * 8);
      vreg = *(const bf16x8*)(vbase + (size_t)qrow * SEQ + (t0 + KT) + qcb * 8);
    }

    // ---- S^T: sc[mq][nt]; kf read ONCE, feeds both mq ----
    f32x4 sc[2][4];
#pragma unroll
    for (int mq = 0; mq < 2; ++mq)
#pragma unroll
      for (int nt = 0; nt < 4; ++nt) sc[mq][nt] = z;

    __builtin_amdgcn_s_setprio(1);
#pragma unroll
    for (int ks = 0; ks < 2; ++ks) {
      bf16x8 kf[4];
#pragma unroll
      for (int nt = 0; nt < 4; ++nt)
        kf[nt] = *(const bf16x8*)(Ks + (nt * 16 + l16) * QSTR + ks * 32 + quad * 8);
#pragma unroll
      for (int mq = 0; mq < 2; ++mq)
#pragma unroll
        for (int nt = 0; nt < 4; ++nt)
          sc[mq][nt] = __builtin_amdgcn_mfma_f32_16x16x32_bf16(kf[nt], qf[mq][ks], sc[mq][nt], 0, 0, 0);
    }
    __builtin_amdgcn_s_setprio(0);

    // mask for t = t0 + nt*16 + quad*4 + v (shared across mq)
    f32x4 mv4[4];
#pragma unroll
    for (int nt = 0; nt < 4; ++nt)
      mv4[nt] = *(const f32x4*)(mask + b * SEQ + t0 + nt * 16 + quad * 4);

    // ---- shifted softmax numerators -> register P fragments (no LDS) ----
    s16x4 pf[2][4];
#pragma unroll
    for (int mq = 0; mq < 2; ++mq) {
#pragma unroll
      for (int nt = 0; nt < 4; ++nt) {
        bf16x4 pk;
#pragma unroll
        for (int v = 0; v < 4; ++v) {
          const float p = __builtin_amdgcn_exp2f(sc[mq][nt][v] * SC2 + mv4[nt][v] * LOG2E - PSHIFT);
          l_part[mq] += p;
          pk[v] = (__bf16)p;
        }
        pf[mq][nt] = as_s16x4(pk);
      }
    }

    // ---- O^T += Vt . P^T via 16x16x16 MFMA: vf4 read ONCE per nt,
    //      feeds both mq (B=pf[mq][nt] direct from registers) ----
    __builtin_amdgcn_s_setprio(1);
#pragma unroll
    for (int nt = 0; nt < 4; ++nt) {
      bf16x4 vf4[4];
#pragma unroll
      for (int db = 0; db < 4; ++db)
        vf4[db] = *(const bf16x4*)(Vts + (db * 16 + l16) * QSTR + nt * 16 + quad * 4);
#pragma unroll
      for (int mq = 0; mq < 2; ++mq)
#pragma unroll
        for (int db = 0; db < 4; ++db)
          o_acc[mq][db] = __builtin_amdgcn_mfma_f32_16x16x16bf16_1k(
              as_s16x4(vf4[db]), pf[mq][nt], o_acc[mq][db], 0, 0, 0);
    }
    __builtin_amdgcn_s_setprio(0);
    __syncthreads();   // Ks/Vts reads done before next staging store
  }

  // ---- epilogue per mq: quad-reduce l, normalize, f32x4 stores ----
#pragma unroll
  for (int mq = 0; mq < 2; ++mq) {
    float l = l_part[mq];
    l += __shfl_xor(l, 16);
    l += __shfl_xor(l, 32);
    const float inv = 1.0f / l;
    const int s = q0 + wave * 32 + mq * 16 + l16;
    float* op = qo + ((size_t)b * SEQ + s) * HID + h * DHEAD + quad * 4;
#pragma unroll
    for (int db = 0; db < 4; ++db) {
      f32x4 val = o_acc[mq][db];
      val[0] *= inv; val[1] *= inv; val[2] *= inv; val[3] *= inv;
      *(f32x4*)(op + db * 16) = val;
    }
  }
}

// ---------------------------------------------------------------------------
extern "C" void kernel_launch(void* const* d_in, const int* in_sizes, int n_in,
                              void* d_out, int out_size, void* d_ws, size_t ws_size,
                              hipStream_t stream) {
  const float* x    = (const float*)d_in[0];
  const float* mask = (const float*)d_in[1];
  const float* sp   = (const float*)d_in[2];
  const float* Wq   = (const float*)d_in[3];
  const float* bq   = (const float*)d_in[4];
  const float* Wk   = (const float*)d_in[5];
  const float* bk   = (const float*)d_in[6];
  const float* Wv   = (const float*)d_in[7];
  const float* bv   = (const float*)d_in[8];
  float* out = (float*)d_out;

  const size_t per = (size_t)BATCH * NHEAD * SEQ * DHEAD;  // 8388608
  const size_t wel = (size_t)3 * HID * HID;                // 3145728
  __bf16* Kws = (__bf16*)d_ws;
  __bf16* Vws = Kws + per;

  // pre-convert path needs K + V + x_bf16 + W_bf16 = 56.6 MB
  const size_t need = (2 * per + per + wel) * sizeof(__bf16);
  if (ws_size >= need) {
    __bf16* xb = Vws + per;
    __bf16* Wb = xb + per;
    // one fused cvt launch: (1048576 + 3*131072) units / 256 = 5632 blocks
    cvt_fused_kernel<<<5632, 256, 0, stream>>>(x, Wq, Wk, Wv, xb, Wb);
    qkv_fused_kernel<<<dim3(8, 64), 512, 0, stream>>>(
        xb, Wb, bq, bk, bv, sp, out, Kws, Vws);
  } else {
    qkv_f32_kernel<<<dim3(8, 64, 3), 512, 0, stream>>>(
        x, Wq, bq, Wk, bk, Wv, bv, sp, out, Kws, Vws);
  }
  attn_kernel<<<dim3(8, 64), 512, 0, stream>>>(out, Kws, Vws, mask);
}

// Round 13
// 294.353 us; speedup vs baseline: 1.0847x; 1.0847x over previous
//
#include <hip/hip_runtime.h>
#include <stdint.h>

#define BATCH 4
#define SEQ   2048
#define NHEAD 16
#define DHEAD 64
#define HID   1024

typedef __bf16 bf16x8 __attribute__((ext_vector_type(8)));
typedef __bf16 bf16x4 __attribute__((ext_vector_type(4)));
typedef float  f32x4  __attribute__((ext_vector_type(4)));

// load 8 contiguous f32, round to bf16x8
__device__ __forceinline__ bf16x8 load8f(const float* p) {
  const f32x4 a = ((const f32x4*)p)[0];
  const f32x4 b = ((const f32x4*)p)[1];
  bf16x8 r;
#pragma unroll
  for (int i = 0; i < 4; ++i) r[i] = (__bf16)a[i];
#pragma unroll
  for (int i = 0; i < 4; ++i) r[4 + i] = (__bf16)b[i];
  return r;
}

// async global->LDS, 16B per lane. LDS dest = wave-uniform base + lane*16.
__device__ __forceinline__ void gload_lds16(const __bf16* g, __bf16* l) {
  __builtin_amdgcn_global_load_lds(
      (const __attribute__((address_space(1))) uint32_t*)g,
      (__attribute__((address_space(3))) uint32_t*)l,
      16, 0, 0);
}

// ---------------------------------------------------------------------------
// fused f32 -> bf16 conversion: x (1048576 units) + Wq/Wk/Wv (131072 each)
// in ONE launch. 8 elements/thread.
// ---------------------------------------------------------------------------
#define XUNITS 1048576
#define WUNITS 131072

__global__ __launch_bounds__(256) void cvt_fused_kernel(
    const float* __restrict__ x,
    const float* __restrict__ Wq, const float* __restrict__ Wk,
    const float* __restrict__ Wv,
    __bf16* __restrict__ xb, __bf16* __restrict__ Wb) {
  const int i = blockIdx.x * 256 + threadIdx.x;
  const float* s;
  __bf16* d;
  if (i < XUNITS) {
    s = x + (size_t)i * 8;
    d = xb + (size_t)i * 8;
  } else {
    const int j = i - XUNITS;
    const int w = j >> 17;          // /131072
    const int o = j & (WUNITS - 1);
    s = (w == 0 ? Wq : w == 1 ? Wk : Wv) + (size_t)o * 8;
    d = Wb + ((size_t)w << 20) + (size_t)o * 8;
  }
  *(bf16x8*)d = load8f(s);
}

#define ASTRIDE 40
#define BK 32

// ---------------------------------------------------------------------------
// qkv FUSED (r9 -- session-best measured ~131 us): one block computes Q, K,
// AND V for its 128x128 tile. A staged once per K-window + 3 B-tiles ride
// the same barrier window -> 24 MFMA per window; A HBM traffic /3. 2-phase
// dbuf, gload_lds w16, T1 XCD swizzle (FETCH-verified 4.5x reduction).
// Q (+RoPE) -> d_out f32; K (+RoPE) -> Kws[B,H,S,DH]; V^T -> Vws[B,H,DH,S].
// ---------------------------------------------------------------------------
__global__ __launch_bounds__(512) void qkv_fused_kernel(
    const __bf16* __restrict__ xb, const __bf16* __restrict__ Wb,
    const float* __restrict__ bq, const float* __restrict__ bk,
    const float* __restrict__ bv, const float* __restrict__ sp,
    float* __restrict__ qout, __bf16* __restrict__ Kws, __bf16* __restrict__ Vws)
{
  const int d    = blockIdx.x + (blockIdx.y << 3);
  const int t    = (d & 7) * 64 + (d >> 3);
  const int n0   = (t & 7) * 128;
  const int m0   = (t >> 3) * 128;

  const int tid  = threadIdx.x;
  const int lane = tid & 63;
  const int quad = lane >> 4;
  const int l16  = lane & 15;
  const int wave = tid >> 6;          // 0..7
  const int wr   = wave >> 1, wc = wave & 1;

  __shared__ __align__(16) __bf16 As[2][128 * BK];      // 16 KB
  __shared__ __align__(16) __bf16 Bs[3][2][128 * BK];   // 48 KB

  const int srow = wave * 16 + (lane >> 2);
  const int scol = (lane & 3) * 8;
  const __bf16* aglb  = xb + (size_t)(m0 + srow) * HID + scol;
  const __bf16* bglb0 = Wb + (size_t)(n0 + srow) * HID + scol;            // Wq
  const __bf16* bglb1 = bglb0 + (size_t)HID * HID;                        // Wk
  const __bf16* bglb2 = bglb0 + (size_t)2 * HID * HID;                    // Wv
  const int woff = wave * 512;        // wave-uniform LDS offset (elements)

  f32x4 aQ[2][4], aK[2][4], aV[2][4];
  const f32x4 z = {0.f, 0.f, 0.f, 0.f};
#pragma unroll
  for (int i = 0; i < 2; ++i)
#pragma unroll
    for (int j = 0; j < 4; ++j) { aQ[i][j] = z; aK[i][j] = z; aV[i][j] = z; }

  // prologue: stage tile 0 into buffer 0, drain
  gload_lds16(aglb,  &As[0][woff]);
  gload_lds16(bglb0, &Bs[0][0][woff]);
  gload_lds16(bglb1, &Bs[1][0][woff]);
  gload_lds16(bglb2, &Bs[2][0][woff]);
  __syncthreads();

#pragma unroll 1
  for (int k0 = 0; k0 < HID; k0 += 2 * BK) {
    // ---- half A: compute buf0, prefetch k0+BK -> buf1 ----
    {
      gload_lds16(aglb  + (k0 + BK), &As[1][woff]);
      gload_lds16(bglb0 + (k0 + BK), &Bs[0][1][woff]);
      gload_lds16(bglb1 + (k0 + BK), &Bs[1][1][woff]);
      gload_lds16(bglb2 + (k0 + BK), &Bs[2][1][woff]);

      bf16x8 af[2];
#pragma unroll
      for (int mt = 0; mt < 2; ++mt)
        af[mt] = *(const bf16x8*)(&As[0][(wr * 32 + mt * 16 + l16) * BK + quad * 8]);
      {
        bf16x8 bfr[4];
#pragma unroll
        for (int nt = 0; nt < 4; ++nt)
          bfr[nt] = *(const bf16x8*)(&Bs[0][0][(wc * 64 + nt * 16 + l16) * BK + quad * 8]);
#pragma unroll
        for (int mt = 0; mt < 2; ++mt)
#pragma unroll
          for (int nt = 0; nt < 4; ++nt)
            aQ[mt][nt] = __builtin_amdgcn_mfma_f32_16x16x32_bf16(af[mt], bfr[nt], aQ[mt][nt], 0, 0, 0);
      }
      {
        bf16x8 bfr[4];
#pragma unroll
        for (int nt = 0; nt < 4; ++nt)
          bfr[nt] = *(const bf16x8*)(&Bs[1][0][(wc * 64 + nt * 16 + l16) * BK + quad * 8]);
#pragma unroll
        for (int mt = 0; mt < 2; ++mt)
#pragma unroll
          for (int nt = 0; nt < 4; ++nt)
            aK[mt][nt] = __builtin_amdgcn_mfma_f32_16x16x32_bf16(af[mt], bfr[nt], aK[mt][nt], 0, 0, 0);
      }
      {
        bf16x8 bfr[4];
#pragma unroll
        for (int nt = 0; nt < 4; ++nt)
          bfr[nt] = *(const bf16x8*)(&Bs[2][0][(wc * 64 + nt * 16 + l16) * BK + quad * 8]);
        // swapped operands -> V^T output
#pragma unroll
        for (int mt = 0; mt < 2; ++mt)
#pragma unroll
          for (int nt = 0; nt < 4; ++nt)
            aV[mt][nt] = __builtin_amdgcn_mfma_f32_16x16x32_bf16(bfr[nt], af[mt], aV[mt][nt], 0, 0, 0);
      }
      __syncthreads();
    }
    // ---- half B: compute buf1, prefetch k0+2*BK -> buf0 ----
    {
      if (k0 + 2 * BK < HID) {
        gload_lds16(aglb  + (k0 + 2 * BK), &As[0][woff]);
        gload_lds16(bglb0 + (k0 + 2 * BK), &Bs[0][0][woff]);
        gload_lds16(bglb1 + (k0 + 2 * BK), &Bs[1][0][woff]);
        gload_lds16(bglb2 + (k0 + 2 * BK), &Bs[2][0][woff]);
      }

      bf16x8 af[2];
#pragma unroll
      for (int mt = 0; mt < 2; ++mt)
        af[mt] = *(const bf16x8*)(&As[1][(wr * 32 + mt * 16 + l16) * BK + quad * 8]);
      {
        bf16x8 bfr[4];
#pragma unroll
        for (int nt = 0; nt < 4; ++nt)
          bfr[nt] = *(const bf16x8*)(&Bs[0][1][(wc * 64 + nt * 16 + l16) * BK + quad * 8]);
#pragma unroll
        for (int mt = 0; mt < 2; ++mt)
#pragma unroll
          for (int nt = 0; nt < 4; ++nt)
            aQ[mt][nt] = __builtin_amdgcn_mfma_f32_16x16x32_bf16(af[mt], bfr[nt], aQ[mt][nt], 0, 0, 0);
      }
      {
        bf16x8 bfr[4];
#pragma unroll
        for (int nt = 0; nt < 4; ++nt)
          bfr[nt] = *(const bf16x8*)(&Bs[1][1][(wc * 64 + nt * 16 + l16) * BK + quad * 8]);
#pragma unroll
        for (int mt = 0; mt < 2; ++mt)
#pragma unroll
          for (int nt = 0; nt < 4; ++nt)
            aK[mt][nt] = __builtin_amdgcn_mfma_f32_16x16x32_bf16(af[mt], bfr[nt], aK[mt][nt], 0, 0, 0);
      }
      {
        bf16x8 bfr[4];
#pragma unroll
        for (int nt = 0; nt < 4; ++nt)
          bfr[nt] = *(const bf16x8*)(&Bs[2][1][(wc * 64 + nt * 16 + l16) * BK + quad * 8]);
#pragma unroll
        for (int mt = 0; mt < 2; ++mt)
#pragma unroll
          for (int nt = 0; nt < 4; ++nt)
            aV[mt][nt] = __builtin_amdgcn_mfma_f32_16x16x32_bf16(bfr[nt], af[mt], aV[mt][nt], 0, 0, 0);
      }
      __syncthreads();
    }
  }

  // ---- epilogue Q: RoPE + f32 store ----
#pragma unroll
  for (int mt = 0; mt < 2; ++mt) {
#pragma unroll
    for (int nt = 0; nt < 4; ++nt) {
      const int n = n0 + wc * 64 + nt * 16 + l16;
      const int h = n >> 6, dd = n & 63;
      const float bval = bq[n];
#pragma unroll
      for (int v = 0; v < 4; ++v) {
        const int m = m0 + wr * 32 + mt * 16 + quad * 4 + v;
        const int b = m >> 11, s = m & (SEQ - 1);
        float val = aQ[mt][nt][v] + bval;
        float p  = __shfl_xor(val, 1);
        float sn = sp[s * 64 + (dd >> 1)];
        float cs = sp[s * 64 + 32 + (dd >> 1)];
        val = val * cs + ((dd & 1) ? p : -p) * sn;
        qout[((size_t)b * SEQ + s) * HID + n] = val;
      }
    }
  }
  // ---- epilogue K: RoPE + bf16 store to Kws[B,H,S,DH] ----
#pragma unroll
  for (int mt = 0; mt < 2; ++mt) {
#pragma unroll
    for (int nt = 0; nt < 4; ++nt) {
      const int n = n0 + wc * 64 + nt * 16 + l16;
      const int h = n >> 6, dd = n & 63;
      const float bval = bk[n];
#pragma unroll
      for (int v = 0; v < 4; ++v) {
        const int m = m0 + wr * 32 + mt * 16 + quad * 4 + v;
        const int b = m >> 11, s = m & (SEQ - 1);
        float val = aK[mt][nt][v] + bval;
        float p  = __shfl_xor(val, 1);
        float sn = sp[s * 64 + (dd >> 1)];
        float cs = sp[s * 64 + 32 + (dd >> 1)];
        val = val * cs + ((dd & 1) ? p : -p) * sn;
        Kws[(((size_t)b * NHEAD + h) * SEQ + s) * DHEAD + dd] = (__bf16)val;
      }
    }
  }
  // ---- epilogue V: V^T bf16 store to Vws[B,H,DH,S] (swapped layout) ----
#pragma unroll
  for (int mt = 0; mt < 2; ++mt) {
#pragma unroll
    for (int nt = 0; nt < 4; ++nt) {
      const int m = m0 + wr * 32 + mt * 16 + l16;   // X-row from l16 (swapped)
      const int b = m >> 11, s = m & (SEQ - 1);
#pragma unroll
      for (int v = 0; v < 4; ++v) {
        const int n = n0 + wc * 64 + nt * 16 + quad * 4 + v;
        const int h = n >> 6, dd = n & 63;
        float val = aV[mt][nt][v] + bv[n];
        Vws[(((size_t)b * NHEAD + h) * DHEAD + dd) * SEQ + s] = (__bf16)val;
      }
    }
  }
}

// ---------------------------------------------------------------------------
// qkv fallback (ws too small): f32 inputs, 512-thread version. (unchanged)
// ---------------------------------------------------------------------------
__global__ __launch_bounds__(512) void qkv_f32_kernel(
    const float* __restrict__ x,
    const float* __restrict__ Wq, const float* __restrict__ bq,
    const float* __restrict__ Wk, const float* __restrict__ bk,
    const float* __restrict__ Wv, const float* __restrict__ bv,
    const float* __restrict__ sp,
    float* __restrict__ qout, __bf16* __restrict__ Kws, __bf16* __restrict__ Vws)
{
  const int widx = blockIdx.z;
  const float* __restrict__ W    = (widx == 0) ? Wq : (widx == 1) ? Wk : Wv;
  const float* __restrict__ bias = (widx == 0) ? bq : (widx == 1) ? bk : bv;

  const int m0   = blockIdx.y * 128;
  const int n0   = blockIdx.x * 128;
  const int tid  = threadIdx.x;
  const int lane = tid & 63;
  const int quad = lane >> 4;
  const int l16  = lane & 15;
  const int wave = tid >> 6;
  const int wr   = wave >> 1, wc = wave & 1;

  __shared__ __align__(16) __bf16 As[128 * ASTRIDE];
  __shared__ __align__(16) __bf16 Bs[128 * ASTRIDE];

  const int srow = tid >> 2;
  const int scb  = tid & 3;

  f32x4 acc[2][4];
  const f32x4 z = {0.f, 0.f, 0.f, 0.f};
#pragma unroll
  for (int i = 0; i < 2; ++i)
#pragma unroll
    for (int j = 0; j < 4; ++j) acc[i][j] = z;

  bf16x8 areg = load8f(x + (size_t)(m0 + srow) * HID + scb * 8);
  bf16x8 breg = load8f(W + (size_t)(n0 + srow) * HID + scb * 8);

  for (int k0 = 0; k0 < HID; k0 += 32) {
    __syncthreads();
    *(bf16x8*)(As + srow * ASTRIDE + scb * 8) = areg;
    *(bf16x8*)(Bs + srow * ASTRIDE + scb * 8) = breg;
    __syncthreads();

    if (k0 + 32 < HID) {
      areg = load8f(x + (size_t)(m0 + srow) * HID + (k0 + 32) + scb * 8);
      breg = load8f(W + (size_t)(n0 + srow) * HID + (k0 + 32) + scb * 8);
    }

    bf16x8 af[2], bfr[4];
#pragma unroll
    for (int mt = 0; mt < 2; ++mt)
      af[mt] = *(const bf16x8*)(As + (wr * 32 + mt * 16 + l16) * ASTRIDE + quad * 8);
#pragma unroll
    for (int nt = 0; nt < 4; ++nt)
      bfr[nt] = *(const bf16x8*)(Bs + (wc * 64 + nt * 16 + l16) * ASTRIDE + quad * 8);

    if (widx < 2) {
#pragma unroll
      for (int mt = 0; mt < 2; ++mt)
#pragma unroll
        for (int nt = 0; nt < 4; ++nt)
          acc[mt][nt] = __builtin_amdgcn_mfma_f32_16x16x32_bf16(af[mt], bfr[nt], acc[mt][nt], 0, 0, 0);
    } else {
#pragma unroll
      for (int mt = 0; mt < 2; ++mt)
#pragma unroll
        for (int nt = 0; nt < 4; ++nt)
          acc[mt][nt] = __builtin_amdgcn_mfma_f32_16x16x32_bf16(bfr[nt], af[mt], acc[mt][nt], 0, 0, 0);
    }
  }

  if (widx < 2) {
#pragma unroll
    for (int mt = 0; mt < 2; ++mt) {
#pragma unroll
      for (int nt = 0; nt < 4; ++nt) {
        const int n = n0 + wc * 64 + nt * 16 + l16;
        const int h = n >> 6, dd = n & 63;
        const float bval = bias[n];
#pragma unroll
        for (int v = 0; v < 4; ++v) {
          const int m = m0 + wr * 32 + mt * 16 + quad * 4 + v;
          const int b = m >> 11, s = m & (SEQ - 1);
          float val = acc[mt][nt][v] + bval;
          float p  = __shfl_xor(val, 1);
          float sn = sp[s * 64 + (dd >> 1)];
          float cs = sp[s * 64 + 32 + (dd >> 1)];
          val = val * cs + ((dd & 1) ? p : -p) * sn;
          if (widx == 0) {
            qout[((size_t)b * SEQ + s) * HID + n] = val;
          } else {
            Kws[(((size_t)b * NHEAD + h) * SEQ + s) * DHEAD + dd] = (__bf16)val;
          }
        }
      }
    }
  } else {
#pragma unroll
    for (int mt = 0; mt < 2; ++mt) {
#pragma unroll
      for (int nt = 0; nt < 4; ++nt) {
        const int m = m0 + wr * 32 + mt * 16 + l16;
        const int b = m >> 11, s = m & (SEQ - 1);
#pragma unroll
        for (int v = 0; v < 4; ++v) {
          const int n = n0 + wc * 64 + nt * 16 + quad * 4 + v;
          const int h = n >> 6, dd = n & 63;
          float val = acc[mt][nt][v] + bias[n];
          Vws[(((size_t)b * NHEAD + h) * DHEAD + dd) * SEQ + s] = (__bf16)val;
        }
      }
    }
  }
}

// ---------------------------------------------------------------------------
// attn: r7/r9-proven structure (best measured 141 us). 512 thr / 8 waves;
// wave owns q-rows [w*16,+16). LDS-staged K/V single-buffer, 2 barriers/
// tile, transposed MFMAs, constant-shift exp2 softmax via wave-private PS,
// setprio around MFMA clusters, T1 XCD swizzle (FETCH 147->33 MB verified).
// Latency-chain-bound at wave-slot cap; all structural variants (dbuf,
// wave-widening, no-staging, PS-free, mq=2) measured neutral-to-worse.
// ---------------------------------------------------------------------------
#define KT 64
#define QSTR 72
#define LOG2E 1.44269504088896340736f
#define PSHIFT 12.0f

__global__ __launch_bounds__(512) void attn_kernel(
    float* __restrict__ qo,
    const __bf16* __restrict__ Kws, const __bf16* __restrict__ Vws,
    const float* __restrict__ mask)
{
  // T1 swizzle (bijective on [0,1024)): XCD = d%8 gets contiguous bh chunk
  const int dsw  = blockIdx.x + (blockIdx.y << 4);
  const int tsw  = (dsw & 7) * 128 + (dsw >> 3);
  const int bh   = tsw >> 4;
  const int q0   = (tsw & 15) * 128;

  const int b    = bh >> 4, h = bh & 15;
  const int tid  = threadIdx.x;
  const int lane = tid & 63;
  const int wave = tid >> 6;          // 0..7
  const int quad = lane >> 4;
  const int l16  = lane & 15;

  __shared__ __align__(16) __bf16 Ks[64 * QSTR];    // [t][k]
  __shared__ __align__(16) __bf16 Vts[64 * QSTR];   // [d][t]
  __shared__ __align__(16) __bf16 PS[128 * QSTR];   // [q][t]

  const __bf16* kbase = Kws + (size_t)bh * SEQ * DHEAD;
  const __bf16* vbase = Vws + (size_t)bh * DHEAD * SEQ;

  // ---- Q fragments (B-operand): q-row = wave*16 + l16 ----
  bf16x8 qf[2];
#pragma unroll
  for (int ks = 0; ks < 2; ++ks)
    qf[ks] = load8f(qo + ((size_t)b * SEQ + q0 + wave * 16 + l16) * HID
                       + h * DHEAD + ks * 32 + quad * 8);

  f32x4 o_acc[4];     // [dblk], C-layout: d=quad*4+v, q=l16
  const f32x4 z = {0.f, 0.f, 0.f, 0.f};
#pragma unroll
  for (int i = 0; i < 4; ++i) o_acc[i] = z;
  float l_part = 0.f;

  const int qrow = tid >> 3;          // 0..63
  const int qcb  = tid & 7;           // col block 0..7

  bf16x8 kreg = *(const bf16x8*)(kbase + (size_t)qrow * DHEAD + qcb * 8);
  bf16x8 vreg = *(const bf16x8*)(vbase + (size_t)qrow * SEQ + qcb * 8);

  const float SC2 = 0.125f * LOG2E;

  for (int t0 = 0; t0 < SEQ; t0 += KT) {
    *(bf16x8*)(Ks  + qrow * QSTR + qcb * 8) = kreg;
    *(bf16x8*)(Vts + qrow * QSTR + qcb * 8) = vreg;
    __syncthreads();

    if (t0 + KT < SEQ) {
      kreg = *(const bf16x8*)(kbase + (size_t)(t0 + KT + qrow) * DHEAD + qcb * 8);
      vreg = *(const bf16x8*)(vbase + (size_t)qrow * SEQ + (t0 + KT) + qcb * 8);
    }

    // ---- S^T: sc[nt] covers t in [nt*16,+16) (rows), q = l16 (cols) ----
    f32x4 sc[4];
#pragma unroll
    for (int nt = 0; nt < 4; ++nt) sc[nt] = z;

    __builtin_amdgcn_s_setprio(1);
#pragma unroll
    for (int ks = 0; ks < 2; ++ks) {
      bf16x8 kf[4];
#pragma unroll
      for (int nt = 0; nt < 4; ++nt)
        kf[nt] = *(const bf16x8*)(Ks + (nt * 16 + l16) * QSTR + ks * 32 + quad * 8);
#pragma unroll
      for (int nt = 0; nt < 4; ++nt)
        sc[nt] = __builtin_amdgcn_mfma_f32_16x16x32_bf16(kf[nt], qf[ks], sc[nt], 0, 0, 0);
    }
    __builtin_amdgcn_s_setprio(0);

    // mask for t = t0 + nt*16 + quad*4 + v (v-contiguous)
    f32x4 mv4[4];
#pragma unroll
    for (int nt = 0; nt < 4; ++nt)
      mv4[nt] = *(const f32x4*)(mask + b * SEQ + t0 + nt * 16 + quad * 4);

    // ---- shifted softmax numerators; b64-packed PS writes ----
    const int prow = wave * 16 + l16;
#pragma unroll
    for (int nt = 0; nt < 4; ++nt) {
      bf16x4 pk;
#pragma unroll
      for (int v = 0; v < 4; ++v) {
        const float p = __builtin_amdgcn_exp2f(sc[nt][v] * SC2 + mv4[nt][v] * LOG2E - PSHIFT);
        l_part += p;
        pk[v] = (__bf16)p;
      }
      *(bf16x4*)(PS + prow * QSTR + nt * 16 + quad * 4) = pk;
    }
    // no barrier: PS rows are wave-private (same-wave DS ops in order)

    // ---- O^T += Vt . P^T : A=Vt[d][t], B=PS[q][t] ----
    __builtin_amdgcn_s_setprio(1);
#pragma unroll
    for (int ks2 = 0; ks2 < 2; ++ks2) {
      bf16x8 pf = *(const bf16x8*)(PS + prow * QSTR + ks2 * 32 + quad * 8);
      bf16x8 vf[4];
#pragma unroll
      for (int db = 0; db < 4; ++db)
        vf[db] = *(const bf16x8*)(Vts + (db * 16 + l16) * QSTR + ks2 * 32 + quad * 8);
#pragma unroll
      for (int db = 0; db < 4; ++db)
        o_acc[db] = __builtin_amdgcn_mfma_f32_16x16x32_bf16(vf[db], pf, o_acc[db], 0, 0, 0);
    }
    __builtin_amdgcn_s_setprio(0);
    __syncthreads();   // Ks/Vts reads done before next staging store
  }

  // ---- row sum: reduce across the 4 quads (lane bits 4,5) ----
  l_part += __shfl_xor(l_part, 16);
  l_part += __shfl_xor(l_part, 32);
  const float inv = 1.0f / l_part;

  // ---- epilogue: normalize, f32x4 stores (d contiguous) ----
  const int s = q0 + wave * 16 + l16;
  float* op = qo + ((size_t)b * SEQ + s) * HID + h * DHEAD + quad * 4;
#pragma unroll
  for (int db = 0; db < 4; ++db) {
    f32x4 val = o_acc[db];
    val[0] *= inv; val[1] *= inv; val[2] *= inv; val[3] *= inv;
    *(f32x4*)(op + db * 16) = val;
  }
}

// ---------------------------------------------------------------------------
extern "C" void kernel_launch(void* const* d_in, const int* in_sizes, int n_in,
                              void* d_out, int out_size, void* d_ws, size_t ws_size,
                              hipStream_t stream) {
  const float* x    = (const float*)d_in[0];
  const float* mask = (const float*)d_in[1];
  const float* sp   = (const float*)d_in[2];
  const float* Wq   = (const float*)d_in[3];
  const float* bq   = (const float*)d_in[4];
  const float* Wk   = (const float*)d_in[5];
  const float* bk   = (const float*)d_in[6];
  const float* Wv   = (const float*)d_in[7];
  const float* bv   = (const float*)d_in[8];
  float* out = (float*)d_out;

  const size_t per = (size_t)BATCH * NHEAD * SEQ * DHEAD;  // 8388608
  const size_t wel = (size_t)3 * HID * HID;                // 3145728
  __bf16* Kws = (__bf16*)d_ws;
  __bf16* Vws = Kws + per;

  // pre-convert path needs K + V + x_bf16 + W_bf16 = 56.6 MB
  const size_t need = (2 * per + per + wel) * sizeof(__bf16);
  if (ws_size >= need) {
    __bf16* xb = Vws + per;
    __bf16* Wb = xb + per;
    // one fused cvt launch: (1048576 + 3*131072) units / 256 = 5632 blocks
    cvt_fused_kernel<<<5632, 256, 0, stream>>>(x, Wq, Wk, Wv, xb, Wb);
    qkv_fused_kernel<<<dim3(8, 64), 512, 0, stream>>>(
        xb, Wb, bq, bk, bv, sp, out, Kws, Vws);
  } else {
    qkv_f32_kernel<<<dim3(8, 64, 3), 512, 0, stream>>>(
        x, Wq, bq, Wk, bk, Wv, bv, sp, out, Kws, Vws);
  }
  attn_kernel<<<dim3(16, 64), 512, 0, stream>>>(out, Kws, Vws, mask);
}